// Round 9
// baseline (195.760 us; speedup 1.0000x reference)
//
#include <hip/hip_runtime.h>
#include <math.h>

namespace {

typedef __attribute__((ext_vector_type(8))) short short8;
typedef __attribute__((ext_vector_type(4))) float f32x4;

constexpr int NL  = 1024;
constexpr int ND  = 512;
constexpr int NH  = 8;
constexpr int NV3 = 36;
constexpr int NCAT = 2560;   // packed projection output cols (2448 used)
constexpr int KF   = 832;    // final-GEMM K (824 used)

constexpr float SCL_S = 0.044194173824159216f; // 1/sqrt(512)
constexpr float SCL_V = 1.0f / 6.0f;           // 1/sqrt(36)

__device__ inline ushort f2bf(float f) {
  uint u = __float_as_uint(f);
  u += 0x7FFFu + ((u >> 16) & 1u);
  return (ushort)(u >> 16);
}
__device__ inline float bf2f(ushort h) { return __uint_as_float((uint)h << 16); }

#define MFMA(a, b, c) __builtin_amdgcn_mfma_f32_16x16x32_bf16((a), (b), (c), 0, 0, 0)

// ---------------------------------------------------------------- k_pack
__global__ __launch_bounds__(256) void k_pack(
    const float* __restrict__ wq, const float* __restrict__ wk,
    const float* __restrict__ wv, const float* __restrict__ wvq,
    const float* __restrict__ wvk, const float* __restrict__ wvv,
    const float* __restrict__ waq, const float* __restrict__ wav,
    const float* __restrict__ w_o, const float* __restrict__ w_vo,
    const float* __restrict__ w_ao,
    ushort* __restrict__ wch, ushort* __restrict__ wcl,
    ushort* __restrict__ wcat2)
{
  __shared__ float t[64][65];
  const int tid = threadIdx.x;
  const int z = blockIdx.z;
  if (z == 0) { if (blockIdx.y >= 8) return; }
  else        { if (blockIdx.x >= 8) return; }
  const int n0 = blockIdx.x * 64, k0 = blockIdx.y * 64;
  const int rr = tid >> 6, cc = tid & 63;

  for (int p = 0; p < 16; ++p) {
    const int kk = k0 + p * 4 + rr;
    const int nn = n0 + cc;
    float val;
    if (z == 0) {
      if (nn < 1536) {
        const float* w = nn < 512 ? wq : (nn < 1024 ? wk : wv);
        val = w[(size_t)kk * 512 + (nn & 511)];
      } else if (nn < 2400) {
        const float* w = nn < 1824 ? wvq : (nn < 2112 ? wvk : wvv);
        val = w[(size_t)kk * 288 + (nn - 1536) % 288];
      } else if (nn < 2424) val = waq[(size_t)kk * 24 + nn - 2400];
      else if (nn < 2448)   val = wav[(size_t)kk * 24 + nn - 2424];
      else val = 0.f;
    } else {
      if (kk < 512)      val = w_o [(size_t)kk * 512 + nn];
      else if (kk < 800) val = w_vo[(size_t)(kk - 512) * 512 + nn];
      else if (kk < 824) val = w_ao[(size_t)(kk - 800) * 512 + nn];
      else val = 0.f;
    }
    t[p * 4 + rr][cc] = val;
  }
  __syncthreads();
  for (int p = 0; p < 16; ++p) {
    const int nn = p * 4 + rr;
    const int kk = cc;
    const float val = t[kk][nn];
    const ushort h16 = f2bf(val);
    if (z == 0) {
      wch[(size_t)(n0 + nn) * 512 + k0 + kk] = h16;
      wcl[(size_t)(n0 + nn) * 512 + k0 + kk] = f2bf(val - bf2f(h16));
    } else {
      wcat2[(size_t)(n0 + nn) * 832 + k0 + kk] = h16;
    }
  }
}

// ---------------------------------------------------------------- k_cvtx
__global__ __launch_bounds__(256) void k_cvtx(const float* __restrict__ x,
                                              ushort* __restrict__ xh,
                                              ushort* __restrict__ xl)
{
  const int i = (blockIdx.x * 256 + threadIdx.x) * 4;
  const float4 v = *(const float4*)&x[i];
  ushort4 h, l;
  h.x = f2bf(v.x); l.x = f2bf(v.x - bf2f(h.x));
  h.y = f2bf(v.y); l.y = f2bf(v.y - bf2f(h.y));
  h.z = f2bf(v.z); l.z = f2bf(v.z - bf2f(h.z));
  h.w = f2bf(v.w); l.w = f2bf(v.w - bf2f(h.w));
  *(ushort4*)&xh[i] = h;
  *(ushort4*)&xl[i] = l;
}

// ---------------------------------------------------------------- k_mm
__global__ __launch_bounds__(256) void k_mm(
    const ushort* __restrict__ Ah, const ushort* __restrict__ Al,
    const ushort* __restrict__ Bh, const ushort* __restrict__ Bl,
    float* __restrict__ Y, int N, int K)
{
  __shared__ __align__(16) ushort Ahs[128][40];
  __shared__ __align__(16) ushort Als[128][40];
  __shared__ __align__(16) ushort Bhs[128][40];
  __shared__ __align__(16) ushort Bls[128][40];
  const int tid = threadIdx.x;
  const int m0 = blockIdx.x * 128, n0 = blockIdx.y * 128;
  const int w = tid >> 6, lane = tid & 63;
  const int wm = (w & 1) * 64, wn = (w >> 1) * 64;
  const int fr = lane & 15, fg = lane >> 4;

  f32x4 acc[4][4];
#pragma unroll
  for (int i = 0; i < 4; ++i)
#pragma unroll
    for (int j = 0; j < 4; ++j) acc[i][j] = (f32x4){0.f, 0.f, 0.f, 0.f};

  const int sr = tid >> 1, sk = (tid & 1) * 16;
  const ushort* agh = Ah + (size_t)(m0 + sr) * K + sk;
  const ushort* agl = Al + (size_t)(m0 + sr) * K + sk;
  const ushort* bgh = Bh + (size_t)(n0 + sr) * K + sk;
  const ushort* bgl = Bl + (size_t)(n0 + sr) * K + sk;
  short8 pah0 = *(const short8*)agh, pah1 = *(const short8*)(agh + 8);
  short8 pal0 = *(const short8*)agl, pal1 = *(const short8*)(agl + 8);
  short8 pbh0 = *(const short8*)bgh, pbh1 = *(const short8*)(bgh + 8);
  short8 pbl0 = *(const short8*)bgl, pbl1 = *(const short8*)(bgl + 8);

  const int NT = K >> 5;
  for (int kt = 0; kt < NT; ++kt) {
    __syncthreads();
    *(short8*)&Ahs[sr][sk] = pah0; *(short8*)&Ahs[sr][sk + 8] = pah1;
    *(short8*)&Als[sr][sk] = pal0; *(short8*)&Als[sr][sk + 8] = pal1;
    *(short8*)&Bhs[sr][sk] = pbh0; *(short8*)&Bhs[sr][sk + 8] = pbh1;
    *(short8*)&Bls[sr][sk] = pbl0; *(short8*)&Bls[sr][sk + 8] = pbl1;
    __syncthreads();
    if (kt + 1 < NT) {
      const size_t off = (size_t)(kt + 1) * 32;
      pah0 = *(const short8*)(agh + off); pah1 = *(const short8*)(agh + off + 8);
      pal0 = *(const short8*)(agl + off); pal1 = *(const short8*)(agl + off + 8);
      pbh0 = *(const short8*)(bgh + off); pbh1 = *(const short8*)(bgh + off + 8);
      pbl0 = *(const short8*)(bgl + off); pbl1 = *(const short8*)(bgl + off + 8);
    }
    short8 fah[4], fal[4], fbh[4], fbl[4];
#pragma unroll
    for (int i = 0; i < 4; ++i) {
      fah[i] = *(const short8*)&Ahs[wm + i * 16 + fr][fg * 8];
      fal[i] = *(const short8*)&Als[wm + i * 16 + fr][fg * 8];
    }
#pragma unroll
    for (int j = 0; j < 4; ++j) {
      fbh[j] = *(const short8*)&Bhs[wn + j * 16 + fr][fg * 8];
      fbl[j] = *(const short8*)&Bls[wn + j * 16 + fr][fg * 8];
    }
#pragma unroll
    for (int i = 0; i < 4; ++i)
#pragma unroll
      for (int j = 0; j < 4; ++j) {
        f32x4 t = MFMA(fah[i], fbh[j], acc[i][j]);
        t = MFMA(fal[i], fbh[j], t);
        t = MFMA(fah[i], fbl[j], t);
        acc[i][j] = t;
      }
  }

  const int rb = fg * 4;
#pragma unroll
  for (int i = 0; i < 4; ++i)
#pragma unroll
    for (int j = 0; j < 4; ++j) {
      const int n = n0 + wn + j * 16 + fr;
#pragma unroll
      for (int r = 0; r < 4; ++r) {
        const int m = m0 + wm + i * 16 + rb + r;
        Y[(size_t)m * N + n] = acc[i][j][r];
      }
    }
}

// ---------------------------------------------------------------- k_fin
__global__ __launch_bounds__(256) void k_fin(
    const ushort* __restrict__ A, const ushort* __restrict__ Bt,
    const float* __restrict__ b_vo, const float* __restrict__ b_ao,
    float* __restrict__ out)
{
  __shared__ __align__(16) ushort As[128][40];
  __shared__ __align__(16) ushort Bs[128][40];
  const int tid = threadIdx.x;
  const int m0 = blockIdx.x * 128, n0 = blockIdx.y * 128;
  const int w = tid >> 6, lane = tid & 63;
  const int wm = (w & 1) * 64, wn = (w >> 1) * 64;
  const int fr = lane & 15, fg = lane >> 4;
  const int K = KF;

  f32x4 acc[4][4];
#pragma unroll
  for (int i = 0; i < 4; ++i)
#pragma unroll
    for (int j = 0; j < 4; ++j) acc[i][j] = (f32x4){0.f, 0.f, 0.f, 0.f};

  const int sr = tid >> 1, sk = (tid & 1) * 16;
  const ushort* ag = A + (size_t)(m0 + sr) * K + sk;
  const ushort* bg = Bt + (size_t)(n0 + sr) * K + sk;
  short8 a0 = *(const short8*)ag;
  short8 a1 = *(const short8*)(ag + 8);
  short8 b0 = *(const short8*)bg;
  short8 b1 = *(const short8*)(bg + 8);

  const int NT = K >> 5;
  for (int kt = 0; kt < NT; ++kt) {
    __syncthreads();
    *(short8*)&As[sr][sk] = a0; *(short8*)&As[sr][sk + 8] = a1;
    *(short8*)&Bs[sr][sk] = b0; *(short8*)&Bs[sr][sk + 8] = b1;
    __syncthreads();
    if (kt + 1 < NT) {
      const ushort* agn = ag + (size_t)(kt + 1) * 32;
      const ushort* bgn = bg + (size_t)(kt + 1) * 32;
      a0 = *(const short8*)agn; a1 = *(const short8*)(agn + 8);
      b0 = *(const short8*)bgn; b1 = *(const short8*)(bgn + 8);
    }
    short8 aF[4], bF[4];
#pragma unroll
    for (int i = 0; i < 4; ++i) aF[i] = *(const short8*)&As[wm + i * 16 + fr][fg * 8];
#pragma unroll
    for (int j = 0; j < 4; ++j) bF[j] = *(const short8*)&Bs[wn + j * 16 + fr][fg * 8];
#pragma unroll
    for (int i = 0; i < 4; ++i)
#pragma unroll
      for (int j = 0; j < 4; ++j)
        acc[i][j] = MFMA(aF[i], bF[j], acc[i][j]);
  }

  const int rb = fg * 4;
#pragma unroll
  for (int j = 0; j < 4; ++j) {
    const int n = n0 + wn + j * 16 + fr;
    const float bias = b_vo[n] + b_ao[n];
#pragma unroll
    for (int i = 0; i < 4; ++i)
#pragma unroll
      for (int r = 0; r < 4; ++r) {
        const int m = m0 + wm + i * 16 + rb + r;
        out[(size_t)m * ND + n] = acc[i][j][r] + bias;
      }
  }
}

// ---------------------------------------------------------------- k_rope
__global__ __launch_bounds__(256) void k_rope(
    const float* __restrict__ Y,
    ushort* __restrict__ qAh, ushort* __restrict__ qAl,
    ushort* __restrict__ kBh, ushort* __restrict__ kBl,
    ushort* __restrict__ Vt)
{
  __shared__ float t0[64][65];
  __shared__ float t1[64][72];
  const int tid = threadIdx.x;
  const int l0 = blockIdx.x * 64, h = blockIdx.y;
  const int b = l0 >> 10, ll0 = l0 & 1023;
  const int bh = b * NH + h;
  const int rr = tid >> 6, cc = tid & 63;
  const float inv = powf(10000.f, -(float)(cc & ~1) / 64.f);
  const bool odd = (cc & 1) != 0;

  // ---- q ----
  for (int p = 0; p < 16; ++p) {
    const int r = p * 4 + rr;
    t0[r][cc] = Y[(size_t)(l0 + r) * NCAT + h * 64 + cc];
  }
  __syncthreads();
  for (int p = 0; p < 16; ++p) {
    const int r = p * 4 + rr;
    float sv, cv;
    __sincosf((float)(ll0 + r) * inv, &sv, &cv);
    const float e = t0[r][cc & ~1], o = t0[r][(cc & ~1) + 1];
    const float val = (odd ? fmaf(e, sv, o * cv) : fmaf(e, cv, -o * sv)) * SCL_S;
    const size_t row = ((size_t)bh * NL + ll0 + r) * 128 + cc;
    const ushort hi = f2bf(val);
    qAh[row] = hi;
    qAl[row] = f2bf(val - bf2f(hi));
  }
  __syncthreads();
  // ---- k ----
  for (int p = 0; p < 16; ++p) {
    const int r = p * 4 + rr;
    t0[r][cc] = Y[(size_t)(l0 + r) * NCAT + 512 + h * 64 + cc];
  }
  __syncthreads();
  for (int p = 0; p < 16; ++p) {
    const int r = p * 4 + rr;
    float sv, cv;
    __sincosf((float)(ll0 + r) * inv, &sv, &cv);
    const float e = t0[r][cc & ~1], o = t0[r][(cc & ~1) + 1];
    const float val = odd ? fmaf(e, sv, o * cv) : fmaf(e, cv, -o * sv);
    const size_t row = ((size_t)bh * NL + ll0 + r) * 128 + cc;
    const ushort hi = f2bf(val);
    kBh[row] = hi;
    kBl[row] = f2bf(val - bf2f(hi));
  }
  // ---- v (transpose to Vt[dim][token]) ----
  for (int p = 0; p < 16; ++p) {
    const int r = p * 4 + rr;
    t1[cc][r] = Y[(size_t)(l0 + r) * NCAT + 1024 + h * 64 + cc];
  }
  __syncthreads();
  for (int p = 0; p < 16; ++p) {
    const int hd = p * 4 + rr;
    Vt[((size_t)bh * 112 + hd) * NL + ll0 + cc] = f2bf(t1[hd][cc]);
  }
  // zero Vt pad rows 103..111
  for (int u = tid; u < 9 * 64; u += 256)
    Vt[((size_t)bh * 112 + 103 + (u >> 6)) * NL + ll0 + (u & 63)] = 0;
}

// ---------------------------------------------------------------- k_rot
__global__ __launch_bounds__(256) void k_rot(
    const float* __restrict__ Y,
    const float* __restrict__ rots, const float* __restrict__ trans,
    const float* __restrict__ mask,
    const float* __restrict__ bvq, const float* __restrict__ bvk,
    const float* __restrict__ bvv, const float* __restrict__ baq,
    const float* __restrict__ bav,
    ushort* __restrict__ qAh, ushort* __restrict__ qAl,
    ushort* __restrict__ kBh, ushort* __restrict__ kBl,
    ushort* __restrict__ Vt,
    float* __restrict__ aq_t, float* __restrict__ penc)
{
  __shared__ float ys[8][912];
  const int tb = blockIdx.x * 8;
  const int b = tb >> 10;
  const int tid = threadIdx.x;

  for (int t = 0; t < 8; ++t)
    for (int n = tid; n < 912; n += 256)
      ys[t][n] = Y[(size_t)(tb + t) * NCAT + 1536 + n];
  __syncthreads();

  for (int u = tid; u < 8 * 288; u += 256) {
    const int t = u / 288, n = u % 288;
    const int l = tb + t, ll = l & (NL - 1);
    const int c = n % 3, base = n - c;
    const int h = n / NV3, m = n % NV3;
    const float r0 = rots[(size_t)l * 9 + c * 3 + 0];
    const float r1 = rots[(size_t)l * 9 + c * 3 + 1];
    const float r2 = rots[(size_t)l * 9 + c * 3 + 2];
    const float vqv = (r0 * (ys[t][base] + bvq[base])
                     + r1 * (ys[t][base + 1] + bvq[base + 1])
                     + r2 * (ys[t][base + 2] + bvq[base + 2])) * SCL_V;
    const float vkv = r0 * (ys[t][288 + base] + bvk[base])
                    + r1 * (ys[t][289 + base] + bvk[base + 1])
                    + r2 * (ys[t][290 + base] + bvk[base + 2]);
    const float vvv = r0 * (ys[t][576 + base] + bvv[base])
                    + r1 * (ys[t][577 + base] + bvv[base + 1])
                    + r2 * (ys[t][578 + base] + bvv[base + 2]);
    const size_t row = ((size_t)(b * NH + h) * NL + ll) * 128 + 64 + m;
    ushort hi = f2bf(vqv);
    qAh[row] = hi; qAl[row] = f2bf(vqv - bf2f(hi));
    hi = f2bf(vkv);
    kBh[row] = hi; kBl[row] = f2bf(vkv - bf2f(hi));
    Vt[((size_t)(b * NH + h) * 112 + 64 + m) * NL + ll] = f2bf(vvv);
  }
  for (int u = tid; u < 8 * 8 * 14; u += 256) {
    const int t = u / 112, rem = u % 112, h = rem / 14, k = rem % 14;
    const int ll = (tb + t) & (NL - 1);
    const size_t row = ((size_t)(b * NH + h) * NL + ll) * 128 + 100 + 2 * k;
    *(uint*)&qAh[row] = 0;
    *(uint*)&qAl[row] = 0;
  }
  for (int u = tid; u < 64; u += 256) {
    const int t = u >> 3, h = u & 7;
    const int l = tb + t, ll = l & (NL - 1);
    const int base = h * 3;
    const size_t tok = (size_t)(b * NH + h) * NL + ll;
#pragma unroll
    for (int c = 0; c < 3; ++c) {
      const float aqv =
          rots[(size_t)l * 9 + c * 3 + 0] * (ys[t][864 + base] + baq[base])
        + rots[(size_t)l * 9 + c * 3 + 1] * (ys[t][865 + base] + baq[base + 1])
        + rots[(size_t)l * 9 + c * 3 + 2] * (ys[t][866 + base] + baq[base + 2])
        + trans[(size_t)l * 3 + c];
      aq_t[((size_t)(b * NH + h) * 3 + c) * NL + ll] = aqv;
    }
#pragma unroll
    for (int k = 0; k < 14; ++k) {
      *(uint*)&kBh[tok * 128 + 100 + 2 * k] = 0;
      *(uint*)&kBl[tok * 128 + 100 + 2 * k] = 0;
    }
  }
  for (int u = tid; u < 8 * 24; u += 256) {
    const int t = u / 24, n = u % 24;
    const int l = tb + t, ll = l & (NL - 1);
    const int c = n % 3, h = n / 3, base = h * 3;
    const float val = rots[(size_t)l * 9 + c * 3 + 0] * (ys[t][888 + base] + bav[base])
                    + rots[(size_t)l * 9 + c * 3 + 1] * (ys[t][889 + base] + bav[base + 1])
                    + rots[(size_t)l * 9 + c * 3 + 2] * (ys[t][890 + base] + bav[base + 2])
                    + trans[(size_t)l * 3 + c];
    Vt[((size_t)(b * NH + h) * 112 + 100 + c) * NL + ll] = f2bf(val);
  }
  for (int u = tid; u < 8; u += 256) {
    const int ll = (tb + u) & (NL - 1);
    penc[(size_t)b * NL + ll] = 1e6f * (1.0f - mask[(size_t)b * NL + ll]);
  }
}

// ---------------------------------------------------------------- k_attn
// Flash MFMA attention, 16 q-rows/block, 4 independent j-quarter waves.
// XCD-swizzled so each XCD owns exactly 2 bh slices (L2-resident K/V).
__global__ __launch_bounds__(256, 3) void k_attn(
    const ushort* __restrict__ qAh, const ushort* __restrict__ qAl,
    const ushort* __restrict__ kBh, const ushort* __restrict__ kBl,
    const ushort* __restrict__ Vt,
    const float* __restrict__ aq_t, const float* __restrict__ penc,
    const float* __restrict__ rots, const float* __restrict__ trans,
    const float* __restrict__ affw,
    ushort* __restrict__ catb)
{
  __shared__ __align__(16) ushort P_s[4][16][72];
  __shared__ float Ocmb[4][16][112];
  __shared__ float mst[4][16], lst[4][16];
  __shared__ float fac[4][16];
  __shared__ float linv[16];

  // XCD-aware swizzle: consecutive blocks round-robin XCDs; give XCD x
  // the bh pair {2x, 2x+1} so K/V working set (~2.4 MB) fits its 4 MB L2.
  const int blk = blockIdx.x;
  const int bh  = (blk & 7) * 2 + (blk >> 9);
  const int i0  = ((blk >> 3) & 63) * 16;
  const int b = bh >> 3, h = bh & 7;
  const int tid = threadIdx.x;
  const int w = tid >> 6, lane = tid & 63;
  const int fr = lane & 15, fg = lane >> 4;

  const float spw = logf(1.0f + expf(affw[h]));

  short8 aQh[4], aQl[4];
  const size_t qrow = ((size_t)bh * NL + i0 + fr) * 128;
#pragma unroll
  for (int ks = 0; ks < 4; ++ks) {
    aQh[ks] = *(const short8*)&qAh[qrow + ks * 32 + fg * 8];
    aQl[ks] = *(const short8*)&qAl[qrow + ks * 32 + fg * 8];
  }

  const float* aqx = aq_t + (size_t)bh * 3 * NL;
  float ai0[4], ai1[4], ai2[4];
#pragma unroll
  for (int r_ = 0; r_ < 4; ++r_) {
    const int row = i0 + fg * 4 + r_;
    ai0[r_] = aqx[row];
    ai1[r_] = aqx[NL + row];
    ai2[r_] = aqx[2 * NL + row];
  }

  float mrun[4], lrun[4];
#pragma unroll
  for (int r_ = 0; r_ < 4; ++r_) { mrun[r_] = -3.0e38f; lrun[r_] = 0.f; }

  f32x4 accO[7];
#pragma unroll
  for (int ct = 0; ct < 7; ++ct) accO[ct] = (f32x4){0.f, 0.f, 0.f, 0.f};

  const size_t kbase = (size_t)bh * NL * 128;
  const size_t vbase = (size_t)bh * 112 * NL;

  for (int jt = 0; jt < 4; ++jt) {
    const int j0 = w * 256 + jt * 64;

    f32x4 accS[4];
#pragma unroll
    for (int ct = 0; ct < 4; ++ct) accS[ct] = (f32x4){0.f, 0.f, 0.f, 0.f};
    __builtin_amdgcn_s_setprio(1);
#pragma unroll
    for (int ct = 0; ct < 4; ++ct) {
      const size_t rowb = kbase + (size_t)(j0 + ct * 16 + fr) * 128;
#pragma unroll
      for (int ks = 0; ks < 4; ++ks) {
        const short8 bh8 = *(const short8*)&kBh[rowb + ks * 32 + fg * 8];
        const short8 bl8 = *(const short8*)&kBl[rowb + ks * 32 + fg * 8];
        f32x4 t = MFMA(aQh[ks], bh8, accS[ct]);
        t = MFMA(aQl[ks], bh8, t);
        t = MFMA(aQh[ks], bl8, t);
        accS[ct] = t;
      }
    }
    __builtin_amdgcn_s_setprio(0);

    // exact fp32 distances + penalty, online softmax (accS reused in place)
    float smax[4] = {-3.0e38f, -3.0e38f, -3.0e38f, -3.0e38f};
#pragma unroll
    for (int ct = 0; ct < 4; ++ct) {
      const int j = j0 + ct * 16 + fr;
      const float aj0 = aqx[j];
      const float aj1 = aqx[NL + j];
      const float aj2v = aqx[2 * NL + j];
      const float pen = penc[(size_t)b * NL + j];
#pragma unroll
      for (int r_ = 0; r_ < 4; ++r_) {
        const float dx = ai0[r_] - aj0;
        const float dy = ai1[r_] - aj1;
        const float dz = ai2[r_] - aj2v;
        const float s = accS[ct][r_]
                      - spw * sqrtf(dx * dx + dy * dy + dz * dz) - pen;
        accS[ct][r_] = s;
        smax[r_] = fmaxf(smax[r_], s);
      }
    }
#pragma unroll
    for (int off = 1; off < 16; off <<= 1) {
#pragma unroll
      for (int r_ = 0; r_ < 4; ++r_)
        smax[r_] = fmaxf(smax[r_], __shfl_xor(smax[r_], off));
    }
    float scale[4], lsum[4];
#pragma unroll
    for (int r_ = 0; r_ < 4; ++r_) {
      const float mnew = fmaxf(mrun[r_], smax[r_]);
      scale[r_] = __expf(mrun[r_] - mnew);
      mrun[r_] = mnew;
      lsum[r_] = 0.f;
    }
#pragma unroll
    for (int ct = 0; ct < 4; ++ct)
#pragma unroll
      for (int r_ = 0; r_ < 4; ++r_) {
        const float p = __expf(accS[ct][r_] - mrun[r_]);
        accS[ct][r_] = p;
        lsum[r_] += p;
      }
#pragma unroll
    for (int off = 1; off < 16; off <<= 1) {
#pragma unroll
      for (int r_ = 0; r_ < 4; ++r_) lsum[r_] += __shfl_xor(lsum[r_], off);
    }
#pragma unroll
    for (int r_ = 0; r_ < 4; ++r_) lrun[r_] = lrun[r_] * scale[r_] + lsum[r_];
#pragma unroll
    for (int ct = 0; ct < 7; ++ct)
#pragma unroll
      for (int r_ = 0; r_ < 4; ++r_) accO[ct][r_] *= scale[r_];

    // P tile to this wave's private LDS region (same-wave ordering via lgkmcnt)
#pragma unroll
    for (int ct = 0; ct < 4; ++ct)
#pragma unroll
      for (int r_ = 0; r_ < 4; ++r_)
        P_s[w][fg * 4 + r_][ct * 16 + fr] = f2bf(accS[ct][r_]);

    const short8 aP0 = *(const short8*)&P_s[w][fr][fg * 8];
    const short8 aP1 = *(const short8*)&P_s[w][fr][32 + fg * 8];
    __builtin_amdgcn_s_setprio(1);
#pragma unroll
    for (int ct = 0; ct < 7; ++ct) {
      const size_t vrow = vbase + (size_t)(ct * 16 + fr) * NL + j0;
      const short8 b0 = *(const short8*)&Vt[vrow + fg * 8];
      const short8 b1 = *(const short8*)&Vt[vrow + 32 + fg * 8];
      f32x4 t = MFMA(aP0, b0, accO[ct]);
      accO[ct] = MFMA(aP1, b1, t);
    }
    __builtin_amdgcn_s_setprio(0);
  }

  // publish partials
#pragma unroll
  for (int ct = 0; ct < 7; ++ct)
#pragma unroll
    for (int r_ = 0; r_ < 4; ++r_)
      Ocmb[w][fg * 4 + r_][ct * 16 + fr] = accO[ct][r_];
  if (fr == 0) {
#pragma unroll
    for (int r_ = 0; r_ < 4; ++r_) {
      mst[w][fg * 4 + r_] = mrun[r_];
      lst[w][fg * 4 + r_] = lrun[r_];
    }
  }
  __syncthreads();

  if (tid < 16) {
    const float m0 = mst[0][tid], m1 = mst[1][tid];
    const float m2 = mst[2][tid], m3 = mst[3][tid];
    const float M = fmaxf(fmaxf(m0, m1), fmaxf(m2, m3));
    const float e0 = __expf(m0 - M), e1 = __expf(m1 - M);
    const float e2 = __expf(m2 - M), e3 = __expf(m3 - M);
    const float L = lst[0][tid] * e0 + lst[1][tid] * e1
                  + lst[2][tid] * e2 + lst[3][tid] * e3;
    fac[0][tid] = e0; fac[1][tid] = e1; fac[2][tid] = e2; fac[3][tid] = e3;
    linv[tid] = 1.0f / L;
  }
  __syncthreads();

  for (int u = tid; u < 16 * 112; u += 256) {
    const int row = u / 112, d = u % 112;
    const float val = (Ocmb[0][row][d] * fac[0][row]
                     + Ocmb[1][row][d] * fac[1][row]
                     + Ocmb[2][row][d] * fac[2][row]
                     + Ocmb[3][row][d] * fac[3][row]) * linv[row];
    Ocmb[0][row][d] = val;
  }
  __syncthreads();

  // epilogue: rotations + catb writes
  for (int u = tid; u < 16 * 103; u += 256) {
    const int lr = u / 103, d = u % 103;
    const int gi = i0 + lr;
    const size_t gl = (size_t)b * NL + gi;
    const float* O = Ocmb[0][lr];
    float val;
    int col;
    if (d < 64) {
      val = O[d];
      col = h * 64 + d;
    } else if (d < 100) {
      const int v3 = d - 64;
      const int n = v3 % 3;
      const int base = 64 + v3 - n;
      val = O[base] * rots[gl * 9 + n] + O[base + 1] * rots[gl * 9 + 3 + n]
          + O[base + 2] * rots[gl * 9 + 6 + n];
      col = 512 + h * NV3 + v3;
    } else {
      const int n = d - 100;
      const float c0 = O[100] - trans[gl * 3 + 0];
      const float c1 = O[101] - trans[gl * 3 + 1];
      const float c2 = O[102] - trans[gl * 3 + 2];
      val = c0 * rots[gl * 9 + n] + c1 * rots[gl * 9 + 3 + n] + c2 * rots[gl * 9 + 6 + n];
      col = 800 + h * 3 + n;
    }
    catb[gl * KF + col] = f2bf(val);
  }
  if (h == 0) {
    for (int u = tid; u < 16 * 8; u += 256)
      catb[((size_t)b * NL + i0 + (u >> 3)) * KF + 824 + (u & 7)] = 0;
  }
}

} // namespace

extern "C" void kernel_launch(void* const* d_in, const int* in_sizes, int n_in,
                              void* d_out, int out_size, void* d_ws, size_t ws_size,
                              hipStream_t stream)
{
  const float* x       = (const float*)d_in[0];
  const float* mask    = (const float*)d_in[1];
  const float* rots    = (const float*)d_in[2];
  const float* trans   = (const float*)d_in[3];
  const float* w_q     = (const float*)d_in[4];
  const float* w_k     = (const float*)d_in[5];
  const float* w_v     = (const float*)d_in[6];
  const float* w_o     = (const float*)d_in[7];
  const float* w_vq_w  = (const float*)d_in[8];
  const float* w_vq_b  = (const float*)d_in[9];
  const float* w_vk_w  = (const float*)d_in[10];
  const float* w_vk_b  = (const float*)d_in[11];
  const float* w_vv_w  = (const float*)d_in[12];
  const float* w_vv_b  = (const float*)d_in[13];
  const float* w_vo_w  = (const float*)d_in[14];
  const float* w_vo_b  = (const float*)d_in[15];
  const float* w_aq_w  = (const float*)d_in[16];
  const float* w_aq_b  = (const float*)d_in[17];
  const float* w_av_w  = (const float*)d_in[18];
  const float* w_av_b  = (const float*)d_in[19];
  const float* w_ao_w  = (const float*)d_in[20];
  const float* w_ao_b  = (const float*)d_in[21];
  const float* aff_w   = (const float*)d_in[22];
  float* out = (float*)d_out;

  char* base = (char*)d_ws;
  ushort* xh  = (ushort*)base;
  ushort* xl  = xh + (size_t)2048 * 512;
  ushort* wch = xl + (size_t)2048 * 512;
  ushort* wcl = wch + (size_t)2560 * 512;
  ushort* qAh = (ushort*)base;                       // 4 MB
  ushort* qAl = qAh + (size_t)16 * 1024 * 128;       // 4 MB
  float*  aq_t = (float*)(qAl + (size_t)16 * 1024 * 128);  // 196 KB
  char* p = base + 9437184;
  ushort* wcat2 = (ushort*)p; p += (size_t)512 * 832 * 2;
  float*  Y     = (float*)p;
  ushort* catb  = (ushort*)Y;
  p += (size_t)2048 * 2560 * 4;
  ushort* kBh = (ushort*)p; p += (size_t)16 * 1024 * 128 * 2;
  ushort* kBl = (ushort*)p; p += (size_t)16 * 1024 * 128 * 2;
  ushort* Vt  = (ushort*)p; p += (size_t)16 * 112 * 1024 * 2;
  float* penc = (float*)p;  p += (size_t)2048 * 4;

  k_pack<<<dim3(40, 13, 2), 256, 0, stream>>>(w_q, w_k, w_v, w_vq_w, w_vk_w,
                                              w_vv_w, w_aq_w, w_av_w,
                                              w_o, w_vo_w, w_ao_w,
                                              wch, wcl, wcat2);
  k_cvtx<<<1024, 256, 0, stream>>>(x, xh, xl);
  k_mm<<<dim3(16, 20), 256, 0, stream>>>(xh, xl, wch, wcl, Y, NCAT, 512);
  k_rope<<<dim3(32, 8), 256, 0, stream>>>(Y, qAh, qAl, kBh, kBl, Vt);
  k_rot<<<256, 256, 0, stream>>>(Y, rots, trans, mask,
                                 w_vq_b, w_vk_b, w_vv_b, w_aq_b, w_av_b,
                                 qAh, qAl, kBh, kBl, Vt, aq_t, penc);
  k_attn<<<1024, 256, 0, stream>>>(qAh, qAl, kBh, kBl, Vt,
                                   aq_t, penc, rots, trans, aff_w, catb);
  k_fin<<<dim3(16, 4), 256, 0, stream>>>(catb, wcat2, w_vo_b, w_ao_b, out);
}

// Round 10
// 158.579 us; speedup vs baseline: 1.2345x; 1.2345x over previous
//
#include <hip/hip_runtime.h>
#include <math.h>

namespace {

typedef __attribute__((ext_vector_type(8))) short short8;
typedef __attribute__((ext_vector_type(4))) float f32x4;

constexpr int NL  = 1024;
constexpr int ND  = 512;
constexpr int NH  = 8;
constexpr int NV3 = 36;
constexpr int NCAT = 2560;   // packed projection output cols (2448 used)
constexpr int KF   = 832;    // final-GEMM K (824 used)

constexpr float SCL_S = 0.044194173824159216f; // 1/sqrt(512)
constexpr float SCL_V = 1.0f / 6.0f;           // 1/sqrt(36)

__device__ inline ushort f2bf(float f) {
  uint u = __float_as_uint(f);
  u += 0x7FFFu + ((u >> 16) & 1u);
  return (ushort)(u >> 16);
}
__device__ inline float bf2f(ushort h) { return __uint_as_float((uint)h << 16); }

#define MFMA(a, b, c) __builtin_amdgcn_mfma_f32_16x16x32_bf16((a), (b), (c), 0, 0, 0)

// ---------------------------------------------------------------- k_pack
__global__ __launch_bounds__(256) void k_pack(
    const float* __restrict__ wq, const float* __restrict__ wk,
    const float* __restrict__ wv, const float* __restrict__ wvq,
    const float* __restrict__ wvk, const float* __restrict__ wvv,
    const float* __restrict__ waq, const float* __restrict__ wav,
    const float* __restrict__ w_o, const float* __restrict__ w_vo,
    const float* __restrict__ w_ao,
    ushort* __restrict__ wch, ushort* __restrict__ wcl,
    ushort* __restrict__ wcat2)
{
  __shared__ float t[64][65];
  const int tid = threadIdx.x;
  const int z = blockIdx.z;
  if (z == 0) { if (blockIdx.y >= 8) return; }
  else        { if (blockIdx.x >= 8) return; }
  const int n0 = blockIdx.x * 64, k0 = blockIdx.y * 64;
  const int rr = tid >> 6, cc = tid & 63;

  for (int p = 0; p < 16; ++p) {
    const int kk = k0 + p * 4 + rr;
    const int nn = n0 + cc;
    float val;
    if (z == 0) {
      if (nn < 1536) {
        const float* w = nn < 512 ? wq : (nn < 1024 ? wk : wv);
        val = w[(size_t)kk * 512 + (nn & 511)];
      } else if (nn < 2400) {
        const float* w = nn < 1824 ? wvq : (nn < 2112 ? wvk : wvv);
        val = w[(size_t)kk * 288 + (nn - 1536) % 288];
      } else if (nn < 2424) val = waq[(size_t)kk * 24 + nn - 2400];
      else if (nn < 2448)   val = wav[(size_t)kk * 24 + nn - 2424];
      else val = 0.f;
    } else {
      if (kk < 512)      val = w_o [(size_t)kk * 512 + nn];
      else if (kk < 800) val = w_vo[(size_t)(kk - 512) * 512 + nn];
      else if (kk < 824) val = w_ao[(size_t)(kk - 800) * 512 + nn];
      else val = 0.f;
    }
    t[p * 4 + rr][cc] = val;
  }
  __syncthreads();
  for (int p = 0; p < 16; ++p) {
    const int nn = p * 4 + rr;
    const int kk = cc;
    const float val = t[kk][nn];
    const ushort h16 = f2bf(val);
    if (z == 0) {
      wch[(size_t)(n0 + nn) * 512 + k0 + kk] = h16;
      wcl[(size_t)(n0 + nn) * 512 + k0 + kk] = f2bf(val - bf2f(h16));
    } else {
      wcat2[(size_t)(n0 + nn) * 832 + k0 + kk] = h16;
    }
  }
}

// ---------------------------------------------------------------- k_cvtx
__global__ __launch_bounds__(256) void k_cvtx(const float* __restrict__ x,
                                              ushort* __restrict__ xh,
                                              ushort* __restrict__ xl)
{
  const int i = (blockIdx.x * 256 + threadIdx.x) * 4;
  const float4 v = *(const float4*)&x[i];
  ushort4 h, l;
  h.x = f2bf(v.x); l.x = f2bf(v.x - bf2f(h.x));
  h.y = f2bf(v.y); l.y = f2bf(v.y - bf2f(h.y));
  h.z = f2bf(v.z); l.z = f2bf(v.z - bf2f(h.z));
  h.w = f2bf(v.w); l.w = f2bf(v.w - bf2f(h.w));
  *(ushort4*)&xh[i] = h;
  *(ushort4*)&xl[i] = l;
}

// ---------------------------------------------------------------- k_mm
__global__ __launch_bounds__(256) void k_mm(
    const ushort* __restrict__ Ah, const ushort* __restrict__ Al,
    const ushort* __restrict__ Bh, const ushort* __restrict__ Bl,
    float* __restrict__ Y, int N, int K)
{
  __shared__ __align__(16) ushort Ahs[128][40];
  __shared__ __align__(16) ushort Als[128][40];
  __shared__ __align__(16) ushort Bhs[128][40];
  __shared__ __align__(16) ushort Bls[128][40];
  const int tid = threadIdx.x;
  const int m0 = blockIdx.x * 128, n0 = blockIdx.y * 128;
  const int w = tid >> 6, lane = tid & 63;
  const int wm = (w & 1) * 64, wn = (w >> 1) * 64;
  const int fr = lane & 15, fg = lane >> 4;

  f32x4 acc[4][4];
#pragma unroll
  for (int i = 0; i < 4; ++i)
#pragma unroll
    for (int j = 0; j < 4; ++j) acc[i][j] = (f32x4){0.f, 0.f, 0.f, 0.f};

  const int sr = tid >> 1, sk = (tid & 1) * 16;
  const ushort* agh = Ah + (size_t)(m0 + sr) * K + sk;
  const ushort* agl = Al + (size_t)(m0 + sr) * K + sk;
  const ushort* bgh = Bh + (size_t)(n0 + sr) * K + sk;
  const ushort* bgl = Bl + (size_t)(n0 + sr) * K + sk;
  short8 pah0 = *(const short8*)agh, pah1 = *(const short8*)(agh + 8);
  short8 pal0 = *(const short8*)agl, pal1 = *(const short8*)(agl + 8);
  short8 pbh0 = *(const short8*)bgh, pbh1 = *(const short8*)(bgh + 8);
  short8 pbl0 = *(const short8*)bgl, pbl1 = *(const short8*)(bgl + 8);

  const int NT = K >> 5;
  for (int kt = 0; kt < NT; ++kt) {
    __syncthreads();
    *(short8*)&Ahs[sr][sk] = pah0; *(short8*)&Ahs[sr][sk + 8] = pah1;
    *(short8*)&Als[sr][sk] = pal0; *(short8*)&Als[sr][sk + 8] = pal1;
    *(short8*)&Bhs[sr][sk] = pbh0; *(short8*)&Bhs[sr][sk + 8] = pbh1;
    *(short8*)&Bls[sr][sk] = pbl0; *(short8*)&Bls[sr][sk + 8] = pbl1;
    __syncthreads();
    if (kt + 1 < NT) {
      const size_t off = (size_t)(kt + 1) * 32;
      pah0 = *(const short8*)(agh + off); pah1 = *(const short8*)(agh + off + 8);
      pal0 = *(const short8*)(agl + off); pal1 = *(const short8*)(agl + off + 8);
      pbh0 = *(const short8*)(bgh + off); pbh1 = *(const short8*)(bgh + off + 8);
      pbl0 = *(const short8*)(bgl + off); pbl1 = *(const short8*)(bgl + off + 8);
    }
    short8 fah[4], fal[4], fbh[4], fbl[4];
#pragma unroll
    for (int i = 0; i < 4; ++i) {
      fah[i] = *(const short8*)&Ahs[wm + i * 16 + fr][fg * 8];
      fal[i] = *(const short8*)&Als[wm + i * 16 + fr][fg * 8];
    }
#pragma unroll
    for (int j = 0; j < 4; ++j) {
      fbh[j] = *(const short8*)&Bhs[wn + j * 16 + fr][fg * 8];
      fbl[j] = *(const short8*)&Bls[wn + j * 16 + fr][fg * 8];
    }
#pragma unroll
    for (int i = 0; i < 4; ++i)
#pragma unroll
      for (int j = 0; j < 4; ++j) {
        f32x4 t = MFMA(fah[i], fbh[j], acc[i][j]);
        t = MFMA(fal[i], fbh[j], t);
        t = MFMA(fah[i], fbl[j], t);
        acc[i][j] = t;
      }
  }

  const int rb = fg * 4;
#pragma unroll
  for (int i = 0; i < 4; ++i)
#pragma unroll
    for (int j = 0; j < 4; ++j) {
      const int n = n0 + wn + j * 16 + fr;
#pragma unroll
      for (int r = 0; r < 4; ++r) {
        const int m = m0 + wm + i * 16 + rb + r;
        Y[(size_t)m * N + n] = acc[i][j][r];
      }
    }
}

// ---------------------------------------------------------------- k_fin
__global__ __launch_bounds__(256) void k_fin(
    const ushort* __restrict__ A, const ushort* __restrict__ Bt,
    const float* __restrict__ b_vo, const float* __restrict__ b_ao,
    float* __restrict__ out)
{
  __shared__ __align__(16) ushort As[128][40];
  __shared__ __align__(16) ushort Bs[128][40];
  const int tid = threadIdx.x;
  const int m0 = blockIdx.x * 128, n0 = blockIdx.y * 128;
  const int w = tid >> 6, lane = tid & 63;
  const int wm = (w & 1) * 64, wn = (w >> 1) * 64;
  const int fr = lane & 15, fg = lane >> 4;
  const int K = KF;

  f32x4 acc[4][4];
#pragma unroll
  for (int i = 0; i < 4; ++i)
#pragma unroll
    for (int j = 0; j < 4; ++j) acc[i][j] = (f32x4){0.f, 0.f, 0.f, 0.f};

  const int sr = tid >> 1, sk = (tid & 1) * 16;
  const ushort* ag = A + (size_t)(m0 + sr) * K + sk;
  const ushort* bg = Bt + (size_t)(n0 + sr) * K + sk;
  short8 a0 = *(const short8*)ag;
  short8 a1 = *(const short8*)(ag + 8);
  short8 b0 = *(const short8*)bg;
  short8 b1 = *(const short8*)(bg + 8);

  const int NT = K >> 5;
  for (int kt = 0; kt < NT; ++kt) {
    __syncthreads();
    *(short8*)&As[sr][sk] = a0; *(short8*)&As[sr][sk + 8] = a1;
    *(short8*)&Bs[sr][sk] = b0; *(short8*)&Bs[sr][sk + 8] = b1;
    __syncthreads();
    if (kt + 1 < NT) {
      const ushort* agn = ag + (size_t)(kt + 1) * 32;
      const ushort* bgn = bg + (size_t)(kt + 1) * 32;
      a0 = *(const short8*)agn; a1 = *(const short8*)(agn + 8);
      b0 = *(const short8*)bgn; b1 = *(const short8*)(bgn + 8);
    }
    short8 aF[4], bF[4];
#pragma unroll
    for (int i = 0; i < 4; ++i) aF[i] = *(const short8*)&As[wm + i * 16 + fr][fg * 8];
#pragma unroll
    for (int j = 0; j < 4; ++j) bF[j] = *(const short8*)&Bs[wn + j * 16 + fr][fg * 8];
#pragma unroll
    for (int i = 0; i < 4; ++i)
#pragma unroll
      for (int j = 0; j < 4; ++j)
        acc[i][j] = MFMA(aF[i], bF[j], acc[i][j]);
  }

  const int rb = fg * 4;
#pragma unroll
  for (int j = 0; j < 4; ++j) {
    const int n = n0 + wn + j * 16 + fr;
    const float bias = b_vo[n] + b_ao[n];
#pragma unroll
    for (int i = 0; i < 4; ++i)
#pragma unroll
      for (int r = 0; r < 4; ++r) {
        const int m = m0 + wm + i * 16 + rb + r;
        out[(size_t)m * ND + n] = acc[i][j][r] + bias;
      }
  }
}

// ---------------------------------------------------------------- k_rope
__global__ __launch_bounds__(256) void k_rope(
    const float* __restrict__ Y,
    ushort* __restrict__ qAh, ushort* __restrict__ qAl,
    ushort* __restrict__ kBh, ushort* __restrict__ Vt)
{
  __shared__ float t0[64][65];
  __shared__ float t1[64][72];
  const int tid = threadIdx.x;
  const int l0 = blockIdx.x * 64, h = blockIdx.y;
  const int b = l0 >> 10, ll0 = l0 & 1023;
  const int bh = b * NH + h;
  const int rr = tid >> 6, cc = tid & 63;
  const float inv = powf(10000.f, -(float)(cc & ~1) / 64.f);
  const bool odd = (cc & 1) != 0;

  // ---- q ----
  for (int p = 0; p < 16; ++p) {
    const int r = p * 4 + rr;
    t0[r][cc] = Y[(size_t)(l0 + r) * NCAT + h * 64 + cc];
  }
  __syncthreads();
  for (int p = 0; p < 16; ++p) {
    const int r = p * 4 + rr;
    float sv, cv;
    __sincosf((float)(ll0 + r) * inv, &sv, &cv);
    const float e = t0[r][cc & ~1], o = t0[r][(cc & ~1) + 1];
    const float val = (odd ? fmaf(e, sv, o * cv) : fmaf(e, cv, -o * sv)) * SCL_S;
    const size_t row = ((size_t)bh * NL + ll0 + r) * 128 + cc;
    const ushort hi = f2bf(val);
    qAh[row] = hi;
    qAl[row] = f2bf(val - bf2f(hi));
  }
  __syncthreads();
  // ---- k (hi plane only) ----
  for (int p = 0; p < 16; ++p) {
    const int r = p * 4 + rr;
    t0[r][cc] = Y[(size_t)(l0 + r) * NCAT + 512 + h * 64 + cc];
  }
  __syncthreads();
  for (int p = 0; p < 16; ++p) {
    const int r = p * 4 + rr;
    float sv, cv;
    __sincosf((float)(ll0 + r) * inv, &sv, &cv);
    const float e = t0[r][cc & ~1], o = t0[r][(cc & ~1) + 1];
    const float val = odd ? fmaf(e, sv, o * cv) : fmaf(e, cv, -o * sv);
    kBh[((size_t)bh * NL + ll0 + r) * 128 + cc] = f2bf(val);
  }
  // ---- v (transpose to Vt[dim][token]) ----
  for (int p = 0; p < 16; ++p) {
    const int r = p * 4 + rr;
    t1[cc][r] = Y[(size_t)(l0 + r) * NCAT + 1024 + h * 64 + cc];
  }
  __syncthreads();
  for (int p = 0; p < 16; ++p) {
    const int hd = p * 4 + rr;
    Vt[((size_t)bh * 112 + hd) * NL + ll0 + cc] = f2bf(t1[hd][cc]);
  }
  // zero Vt pad rows 103..111
  for (int u = tid; u < 9 * 64; u += 256)
    Vt[((size_t)bh * 112 + 103 + (u >> 6)) * NL + ll0 + (u & 63)] = 0;
}

// ---------------------------------------------------------------- k_rot
__global__ __launch_bounds__(256) void k_rot(
    const float* __restrict__ Y,
    const float* __restrict__ rots, const float* __restrict__ trans,
    const float* __restrict__ mask,
    const float* __restrict__ bvq, const float* __restrict__ bvk,
    const float* __restrict__ bvv, const float* __restrict__ baq,
    const float* __restrict__ bav,
    ushort* __restrict__ qAh, ushort* __restrict__ qAl,
    ushort* __restrict__ kBh, ushort* __restrict__ Vt,
    float* __restrict__ aq_t, float* __restrict__ penc)
{
  __shared__ float ys[8][912];
  const int tb = blockIdx.x * 8;
  const int b = tb >> 10;
  const int tid = threadIdx.x;

  for (int t = 0; t < 8; ++t)
    for (int n = tid; n < 912; n += 256)
      ys[t][n] = Y[(size_t)(tb + t) * NCAT + 1536 + n];
  __syncthreads();

  for (int u = tid; u < 8 * 288; u += 256) {
    const int t = u / 288, n = u % 288;
    const int l = tb + t, ll = l & (NL - 1);
    const int c = n % 3, base = n - c;
    const int h = n / NV3, m = n % NV3;
    const float r0 = rots[(size_t)l * 9 + c * 3 + 0];
    const float r1 = rots[(size_t)l * 9 + c * 3 + 1];
    const float r2 = rots[(size_t)l * 9 + c * 3 + 2];
    const float vqv = (r0 * (ys[t][base] + bvq[base])
                     + r1 * (ys[t][base + 1] + bvq[base + 1])
                     + r2 * (ys[t][base + 2] + bvq[base + 2])) * SCL_V;
    const float vkv = r0 * (ys[t][288 + base] + bvk[base])
                    + r1 * (ys[t][289 + base] + bvk[base + 1])
                    + r2 * (ys[t][290 + base] + bvk[base + 2]);
    const float vvv = r0 * (ys[t][576 + base] + bvv[base])
                    + r1 * (ys[t][577 + base] + bvv[base + 1])
                    + r2 * (ys[t][578 + base] + bvv[base + 2]);
    const size_t row = ((size_t)(b * NH + h) * NL + ll) * 128 + 64 + m;
    ushort hi = f2bf(vqv);
    qAh[row] = hi; qAl[row] = f2bf(vqv - bf2f(hi));
    kBh[row] = f2bf(vkv);
    Vt[((size_t)(b * NH + h) * 112 + 64 + m) * NL + ll] = f2bf(vvv);
  }
  for (int u = tid; u < 8 * 8 * 14; u += 256) {
    const int t = u / 112, rem = u % 112, h = rem / 14, k = rem % 14;
    const int ll = (tb + t) & (NL - 1);
    const size_t row = ((size_t)(b * NH + h) * NL + ll) * 128 + 100 + 2 * k;
    *(uint*)&qAh[row] = 0;
    *(uint*)&qAl[row] = 0;
  }
  for (int u = tid; u < 64; u += 256) {
    const int t = u >> 3, h = u & 7;
    const int l = tb + t, ll = l & (NL - 1);
    const int base = h * 3;
    const size_t tok = (size_t)(b * NH + h) * NL + ll;
#pragma unroll
    for (int c = 0; c < 3; ++c) {
      const float aqv =
          rots[(size_t)l * 9 + c * 3 + 0] * (ys[t][864 + base] + baq[base])
        + rots[(size_t)l * 9 + c * 3 + 1] * (ys[t][865 + base] + baq[base + 1])
        + rots[(size_t)l * 9 + c * 3 + 2] * (ys[t][866 + base] + baq[base + 2])
        + trans[(size_t)l * 3 + c];
      aq_t[((size_t)(b * NH + h) * 3 + c) * NL + ll] = aqv;
    }
#pragma unroll
    for (int k = 0; k < 14; ++k)
      *(uint*)&kBh[tok * 128 + 100 + 2 * k] = 0;
  }
  for (int u = tid; u < 8 * 24; u += 256) {
    const int t = u / 24, n = u % 24;
    const int l = tb + t, ll = l & (NL - 1);
    const int c = n % 3, h = n / 3, base = h * 3;
    const float val = rots[(size_t)l * 9 + c * 3 + 0] * (ys[t][888 + base] + bav[base])
                    + rots[(size_t)l * 9 + c * 3 + 1] * (ys[t][889 + base] + bav[base + 1])
                    + rots[(size_t)l * 9 + c * 3 + 2] * (ys[t][890 + base] + bav[base + 2])
                    + trans[(size_t)l * 3 + c];
    Vt[((size_t)(b * NH + h) * 112 + 100 + c) * NL + ll] = f2bf(val);
  }
  for (int u = tid; u < 8; u += 256) {
    const int ll = (tb + u) & (NL - 1);
    penc[(size_t)b * NL + ll] = 1e6f * (1.0f - mask[(size_t)b * NL + ll]);
  }
}

// ---------------------------------------------------------------- k_attn
// Flash MFMA attention, 16 q-rows/block, 4 independent j-quarter waves.
// XCD-swizzled (each XCD owns 2 bh slices -> K/V ~1.0 MB L2-resident).
// 2-term split QK: (q_hi + q_lo) x k_hi; K lo-plane dropped.
__global__ __launch_bounds__(256) void k_attn(
    const ushort* __restrict__ qAh, const ushort* __restrict__ qAl,
    const ushort* __restrict__ kBh, const ushort* __restrict__ Vt,
    const float* __restrict__ aq_t, const float* __restrict__ penc,
    const float* __restrict__ rots, const float* __restrict__ trans,
    const float* __restrict__ affw,
    ushort* __restrict__ catb)
{
  __shared__ __align__(16) ushort P_s[4][16][72];
  __shared__ float Ocmb[4][16][112];
  __shared__ float mst[4][16], lst[4][16];
  __shared__ float fac[4][16];
  __shared__ float linv[16];

  const int blk = blockIdx.x;
  const int bh  = (blk & 7) * 2 + (blk >> 9);
  const int i0  = ((blk >> 3) & 63) * 16;
  const int b = bh >> 3, h = bh & 7;
  const int tid = threadIdx.x;
  const int w = tid >> 6, lane = tid & 63;
  const int fr = lane & 15, fg = lane >> 4;

  const float spw = logf(1.0f + expf(affw[h]));

  short8 aQh[4], aQl[4];
  const size_t qrow = ((size_t)bh * NL + i0 + fr) * 128;
#pragma unroll
  for (int ks = 0; ks < 4; ++ks) {
    aQh[ks] = *(const short8*)&qAh[qrow + ks * 32 + fg * 8];
    aQl[ks] = *(const short8*)&qAl[qrow + ks * 32 + fg * 8];
  }

  const float* aqx = aq_t + (size_t)bh * 3 * NL;
  float ai0[4], ai1[4], ai2[4];
#pragma unroll
  for (int r_ = 0; r_ < 4; ++r_) {
    const int row = i0 + fg * 4 + r_;
    ai0[r_] = aqx[row];
    ai1[r_] = aqx[NL + row];
    ai2[r_] = aqx[2 * NL + row];
  }

  float mrun[4], lrun[4];
#pragma unroll
  for (int r_ = 0; r_ < 4; ++r_) { mrun[r_] = -3.0e38f; lrun[r_] = 0.f; }

  f32x4 accO[7];
#pragma unroll
  for (int ct = 0; ct < 7; ++ct) accO[ct] = (f32x4){0.f, 0.f, 0.f, 0.f};

  const size_t kbase = (size_t)bh * NL * 128;
  const size_t vbase = (size_t)bh * 112 * NL;

  for (int jt = 0; jt < 4; ++jt) {
    const int j0 = w * 256 + jt * 64;

    f32x4 accS[4];
#pragma unroll
    for (int ct = 0; ct < 4; ++ct) accS[ct] = (f32x4){0.f, 0.f, 0.f, 0.f};
#pragma unroll
    for (int ct = 0; ct < 4; ++ct) {
      const size_t rowb = kbase + (size_t)(j0 + ct * 16 + fr) * 128;
#pragma unroll
      for (int ks = 0; ks < 4; ++ks) {
        const short8 bh8 = *(const short8*)&kBh[rowb + ks * 32 + fg * 8];
        f32x4 t = MFMA(aQh[ks], bh8, accS[ct]);
        accS[ct] = MFMA(aQl[ks], bh8, t);
      }
    }

    // exact fp32 distances + penalty, online softmax (accS reused in place)
    float smax[4] = {-3.0e38f, -3.0e38f, -3.0e38f, -3.0e38f};
#pragma unroll
    for (int ct = 0; ct < 4; ++ct) {
      const int j = j0 + ct * 16 + fr;
      const float aj0 = aqx[j];
      const float aj1 = aqx[NL + j];
      const float aj2v = aqx[2 * NL + j];
      const float pen = penc[(size_t)b * NL + j];
#pragma unroll
      for (int r_ = 0; r_ < 4; ++r_) {
        const float dx = ai0[r_] - aj0;
        const float dy = ai1[r_] - aj1;
        const float dz = ai2[r_] - aj2v;
        const float s = accS[ct][r_]
                      - spw * sqrtf(dx * dx + dy * dy + dz * dz) - pen;
        accS[ct][r_] = s;
        smax[r_] = fmaxf(smax[r_], s);
      }
    }
#pragma unroll
    for (int off = 1; off < 16; off <<= 1) {
#pragma unroll
      for (int r_ = 0; r_ < 4; ++r_)
        smax[r_] = fmaxf(smax[r_], __shfl_xor(smax[r_], off));
    }
    float scale[4], lsum[4];
#pragma unroll
    for (int r_ = 0; r_ < 4; ++r_) {
      const float mnew = fmaxf(mrun[r_], smax[r_]);
      scale[r_] = __expf(mrun[r_] - mnew);
      mrun[r_] = mnew;
      lsum[r_] = 0.f;
    }
#pragma unroll
    for (int ct = 0; ct < 4; ++ct)
#pragma unroll
      for (int r_ = 0; r_ < 4; ++r_) {
        const float p = __expf(accS[ct][r_] - mrun[r_]);
        accS[ct][r_] = p;
        lsum[r_] += p;
      }
#pragma unroll
    for (int off = 1; off < 16; off <<= 1) {
#pragma unroll
      for (int r_ = 0; r_ < 4; ++r_) lsum[r_] += __shfl_xor(lsum[r_], off);
    }
#pragma unroll
    for (int r_ = 0; r_ < 4; ++r_) lrun[r_] = lrun[r_] * scale[r_] + lsum[r_];
#pragma unroll
    for (int ct = 0; ct < 7; ++ct)
#pragma unroll
      for (int r_ = 0; r_ < 4; ++r_) accO[ct][r_] *= scale[r_];

    // P tile to this wave's private LDS region (same-wave ordering via lgkmcnt)
#pragma unroll
    for (int ct = 0; ct < 4; ++ct)
#pragma unroll
      for (int r_ = 0; r_ < 4; ++r_)
        P_s[w][fg * 4 + r_][ct * 16 + fr] = f2bf(accS[ct][r_]);

    const short8 aP0 = *(const short8*)&P_s[w][fr][fg * 8];
    const short8 aP1 = *(const short8*)&P_s[w][fr][32 + fg * 8];
#pragma unroll
    for (int ct = 0; ct < 7; ++ct) {
      const size_t vrow = vbase + (size_t)(ct * 16 + fr) * NL + j0;
      const short8 b0 = *(const short8*)&Vt[vrow + fg * 8];
      const short8 b1 = *(const short8*)&Vt[vrow + 32 + fg * 8];
      f32x4 t = MFMA(aP0, b0, accO[ct]);
      accO[ct] = MFMA(aP1, b1, t);
    }
  }

  // publish partials
#pragma unroll
  for (int ct = 0; ct < 7; ++ct)
#pragma unroll
    for (int r_ = 0; r_ < 4; ++r_)
      Ocmb[w][fg * 4 + r_][ct * 16 + fr] = accO[ct][r_];
  if (fr == 0) {
#pragma unroll
    for (int r_ = 0; r_ < 4; ++r_) {
      mst[w][fg * 4 + r_] = mrun[r_];
      lst[w][fg * 4 + r_] = lrun[r_];
    }
  }
  __syncthreads();

  if (tid < 16) {
    const float m0 = mst[0][tid], m1 = mst[1][tid];
    const float m2 = mst[2][tid], m3 = mst[3][tid];
    const float M = fmaxf(fmaxf(m0, m1), fmaxf(m2, m3));
    const float e0 = __expf(m0 - M), e1 = __expf(m1 - M);
    const float e2 = __expf(m2 - M), e3 = __expf(m3 - M);
    const float L = lst[0][tid] * e0 + lst[1][tid] * e1
                  + lst[2][tid] * e2 + lst[3][tid] * e3;
    fac[0][tid] = e0; fac[1][tid] = e1; fac[2][tid] = e2; fac[3][tid] = e3;
    linv[tid] = 1.0f / L;
  }
  __syncthreads();

  for (int u = tid; u < 16 * 112; u += 256) {
    const int row = u / 112, d = u % 112;
    const float val = (Ocmb[0][row][d] * fac[0][row]
                     + Ocmb[1][row][d] * fac[1][row]
                     + Ocmb[2][row][d] * fac[2][row]
                     + Ocmb[3][row][d] * fac[3][row]) * linv[row];
    Ocmb[0][row][d] = val;
  }
  __syncthreads();

  // epilogue: rotations + catb writes
  for (int u = tid; u < 16 * 103; u += 256) {
    const int lr = u / 103, d = u % 103;
    const int gi = i0 + lr;
    const size_t gl = (size_t)b * NL + gi;
    const float* O = Ocmb[0][lr];
    float val;
    int col;
    if (d < 64) {
      val = O[d];
      col = h * 64 + d;
    } else if (d < 100) {
      const int v3 = d - 64;
      const int n = v3 % 3;
      const int base = 64 + v3 - n;
      val = O[base] * rots[gl * 9 + n] + O[base + 1] * rots[gl * 9 + 3 + n]
          + O[base + 2] * rots[gl * 9 + 6 + n];
      col = 512 + h * NV3 + v3;
    } else {
      const int n = d - 100;
      const float c0 = O[100] - trans[gl * 3 + 0];
      const float c1 = O[101] - trans[gl * 3 + 1];
      const float c2 = O[102] - trans[gl * 3 + 2];
      val = c0 * rots[gl * 9 + n] + c1 * rots[gl * 9 + 3 + n] + c2 * rots[gl * 9 + 6 + n];
      col = 800 + h * 3 + n;
    }
    catb[gl * KF + col] = f2bf(val);
  }
  if (h == 0) {
    for (int u = tid; u < 16 * 8; u += 256)
      catb[((size_t)b * NL + i0 + (u >> 3)) * KF + 824 + (u & 7)] = 0;
  }
}

} // namespace

extern "C" void kernel_launch(void* const* d_in, const int* in_sizes, int n_in,
                              void* d_out, int out_size, void* d_ws, size_t ws_size,
                              hipStream_t stream)
{
  const float* x       = (const float*)d_in[0];
  const float* mask    = (const float*)d_in[1];
  const float* rots    = (const float*)d_in[2];
  const float* trans   = (const float*)d_in[3];
  const float* w_q     = (const float*)d_in[4];
  const float* w_k     = (const float*)d_in[5];
  const float* w_v     = (const float*)d_in[6];
  const float* w_o     = (const float*)d_in[7];
  const float* w_vq_w  = (const float*)d_in[8];
  const float* w_vq_b  = (const float*)d_in[9];
  const float* w_vk_w  = (const float*)d_in[10];
  const float* w_vk_b  = (const float*)d_in[11];
  const float* w_vv_w  = (const float*)d_in[12];
  const float* w_vv_b  = (const float*)d_in[13];
  const float* w_vo_w  = (const float*)d_in[14];
  const float* w_vo_b  = (const float*)d_in[15];
  const float* w_aq_w  = (const float*)d_in[16];
  const float* w_aq_b  = (const float*)d_in[17];
  const float* w_av_w  = (const float*)d_in[18];
  const float* w_av_b  = (const float*)d_in[19];
  const float* w_ao_w  = (const float*)d_in[20];
  const float* w_ao_b  = (const float*)d_in[21];
  const float* aff_w   = (const float*)d_in[22];
  float* out = (float*)d_out;

  char* base = (char*)d_ws;
  ushort* xh  = (ushort*)base;
  ushort* xl  = xh + (size_t)2048 * 512;
  ushort* wch = xl + (size_t)2048 * 512;
  ushort* wcl = wch + (size_t)2560 * 512;
  ushort* qAh = (ushort*)base;                       // 4 MB
  ushort* qAl = qAh + (size_t)16 * 1024 * 128;       // 4 MB
  float*  aq_t = (float*)(qAl + (size_t)16 * 1024 * 128);  // 196 KB
  char* p = base + 9437184;
  ushort* wcat2 = (ushort*)p; p += (size_t)512 * 832 * 2;
  float*  Y     = (float*)p;
  ushort* catb  = (ushort*)Y;
  p += (size_t)2048 * 2560 * 4;
  ushort* kBh = (ushort*)p; p += (size_t)16 * 1024 * 128 * 2;
  ushort* Vt  = (ushort*)p; p += (size_t)16 * 112 * 1024 * 2;
  float* penc = (float*)p;  p += (size_t)2048 * 4;

  k_pack<<<dim3(40, 13, 2), 256, 0, stream>>>(w_q, w_k, w_v, w_vq_w, w_vk_w,
                                              w_vv_w, w_aq_w, w_av_w,
                                              w_o, w_vo_w, w_ao_w,
                                              wch, wcl, wcat2);
  k_cvtx<<<1024, 256, 0, stream>>>(x, xh, xl);
  k_mm<<<dim3(16, 20), 256, 0, stream>>>(xh, xl, wch, wcl, Y, NCAT, 512);
  k_rope<<<dim3(32, 8), 256, 0, stream>>>(Y, qAh, qAl, kBh, Vt);
  k_rot<<<256, 256, 0, stream>>>(Y, rots, trans, mask,
                                 w_vq_b, w_vk_b, w_vv_b, w_aq_b, w_av_b,
                                 qAh, qAl, kBh, Vt, aq_t, penc);
  k_attn<<<1024, 256, 0, stream>>>(qAh, qAl, kBh, Vt,
                                   aq_t, penc, rots, trans, aff_w, catb);
  k_fin<<<dim3(16, 4), 256, 0, stream>>>(catb, wcat2, w_vo_b, w_ao_b, out);
}

// Round 11
// 155.226 us; speedup vs baseline: 1.2611x; 1.0216x over previous
//
#include <hip/hip_runtime.h>
#include <math.h>

namespace {

typedef __attribute__((ext_vector_type(8))) short short8;
typedef __attribute__((ext_vector_type(4))) float f32x4;

constexpr int NL  = 1024;
constexpr int ND  = 512;
constexpr int NH  = 8;
constexpr int NV3 = 36;
constexpr int NCAT = 2560;   // packed projection output cols (2448 used)
constexpr int KF   = 832;    // final-GEMM K (824 used)

constexpr float SCL_S = 0.044194173824159216f; // 1/sqrt(512)
constexpr float SCL_V = 1.0f / 6.0f;           // 1/sqrt(36)

__device__ inline ushort f2bf(float f) {
  uint u = __float_as_uint(f);
  u += 0x7FFFu + ((u >> 16) & 1u);
  return (ushort)(u >> 16);
}
__device__ inline float bf2f(ushort h) { return __uint_as_float((uint)h << 16); }

#define MFMA(a, b, c) __builtin_amdgcn_mfma_f32_16x16x32_bf16((a), (b), (c), 0, 0, 0)

// ---------------------------------------------------------------- k_pack
__global__ __launch_bounds__(256) void k_pack(
    const float* __restrict__ wq, const float* __restrict__ wk,
    const float* __restrict__ wv, const float* __restrict__ wvq,
    const float* __restrict__ wvk, const float* __restrict__ wvv,
    const float* __restrict__ waq, const float* __restrict__ wav,
    const float* __restrict__ w_o, const float* __restrict__ w_vo,
    const float* __restrict__ w_ao,
    ushort* __restrict__ wch, ushort* __restrict__ wcl,
    ushort* __restrict__ wcat2)
{
  __shared__ float t[64][65];
  const int tid = threadIdx.x;
  const int z = blockIdx.z;
  if (z == 0) { if (blockIdx.y >= 8) return; }
  else        { if (blockIdx.x >= 8) return; }
  const int n0 = blockIdx.x * 64, k0 = blockIdx.y * 64;
  const int rr = tid >> 6, cc = tid & 63;

  for (int p = 0; p < 16; ++p) {
    const int kk = k0 + p * 4 + rr;
    const int nn = n0 + cc;
    float val;
    if (z == 0) {
      if (nn < 1536) {
        const float* w = nn < 512 ? wq : (nn < 1024 ? wk : wv);
        val = w[(size_t)kk * 512 + (nn & 511)];
      } else if (nn < 2400) {
        const float* w = nn < 1824 ? wvq : (nn < 2112 ? wvk : wvv);
        val = w[(size_t)kk * 288 + (nn - 1536) % 288];
      } else if (nn < 2424) val = waq[(size_t)kk * 24 + nn - 2400];
      else if (nn < 2448)   val = wav[(size_t)kk * 24 + nn - 2424];
      else val = 0.f;
    } else {
      if (kk < 512)      val = w_o [(size_t)kk * 512 + nn];
      else if (kk < 800) val = w_vo[(size_t)(kk - 512) * 512 + nn];
      else if (kk < 824) val = w_ao[(size_t)(kk - 800) * 512 + nn];
      else val = 0.f;
    }
    t[p * 4 + rr][cc] = val;
  }
  __syncthreads();
  for (int p = 0; p < 16; ++p) {
    const int nn = p * 4 + rr;
    const int kk = cc;
    const float val = t[kk][nn];
    const ushort h16 = f2bf(val);
    if (z == 0) {
      wch[(size_t)(n0 + nn) * 512 + k0 + kk] = h16;
      wcl[(size_t)(n0 + nn) * 512 + k0 + kk] = f2bf(val - bf2f(h16));
    } else {
      wcat2[(size_t)(n0 + nn) * 832 + k0 + kk] = h16;
    }
  }
}

// ---------------------------------------------------------------- k_cvtx
__global__ __launch_bounds__(256) void k_cvtx(const float* __restrict__ x,
                                              ushort* __restrict__ xh,
                                              ushort* __restrict__ xl)
{
  const int i = (blockIdx.x * 256 + threadIdx.x) * 4;
  const float4 v = *(const float4*)&x[i];
  ushort4 h, l;
  h.x = f2bf(v.x); l.x = f2bf(v.x - bf2f(h.x));
  h.y = f2bf(v.y); l.y = f2bf(v.y - bf2f(h.y));
  h.z = f2bf(v.z); l.z = f2bf(v.z - bf2f(h.z));
  h.w = f2bf(v.w); l.w = f2bf(v.w - bf2f(h.w));
  *(ushort4*)&xh[i] = h;
  *(ushort4*)&xl[i] = l;
}

// ---------------------------------------------------------------- k_mm
__global__ __launch_bounds__(256) void k_mm(
    const ushort* __restrict__ Ah, const ushort* __restrict__ Al,
    const ushort* __restrict__ Bh, const ushort* __restrict__ Bl,
    float* __restrict__ Y, int N, int K)
{
  __shared__ __align__(16) ushort Ahs[128][40];
  __shared__ __align__(16) ushort Als[128][40];
  __shared__ __align__(16) ushort Bhs[128][40];
  __shared__ __align__(16) ushort Bls[128][40];
  const int tid = threadIdx.x;
  const int m0 = blockIdx.x * 128, n0 = blockIdx.y * 128;
  const int w = tid >> 6, lane = tid & 63;
  const int wm = (w & 1) * 64, wn = (w >> 1) * 64;
  const int fr = lane & 15, fg = lane >> 4;

  f32x4 acc[4][4];
#pragma unroll
  for (int i = 0; i < 4; ++i)
#pragma unroll
    for (int j = 0; j < 4; ++j) acc[i][j] = (f32x4){0.f, 0.f, 0.f, 0.f};

  const int sr = tid >> 1, sk = (tid & 1) * 16;
  const ushort* agh = Ah + (size_t)(m0 + sr) * K + sk;
  const ushort* agl = Al + (size_t)(m0 + sr) * K + sk;
  const ushort* bgh = Bh + (size_t)(n0 + sr) * K + sk;
  const ushort* bgl = Bl + (size_t)(n0 + sr) * K + sk;
  short8 pah0 = *(const short8*)agh, pah1 = *(const short8*)(agh + 8);
  short8 pal0 = *(const short8*)agl, pal1 = *(const short8*)(agl + 8);
  short8 pbh0 = *(const short8*)bgh, pbh1 = *(const short8*)(bgh + 8);
  short8 pbl0 = *(const short8*)bgl, pbl1 = *(const short8*)(bgl + 8);

  const int NT = K >> 5;
  for (int kt = 0; kt < NT; ++kt) {
    __syncthreads();
    *(short8*)&Ahs[sr][sk] = pah0; *(short8*)&Ahs[sr][sk + 8] = pah1;
    *(short8*)&Als[sr][sk] = pal0; *(short8*)&Als[sr][sk + 8] = pal1;
    *(short8*)&Bhs[sr][sk] = pbh0; *(short8*)&Bhs[sr][sk + 8] = pbh1;
    *(short8*)&Bls[sr][sk] = pbl0; *(short8*)&Bls[sr][sk + 8] = pbl1;
    __syncthreads();
    if (kt + 1 < NT) {
      const size_t off = (size_t)(kt + 1) * 32;
      pah0 = *(const short8*)(agh + off); pah1 = *(const short8*)(agh + off + 8);
      pal0 = *(const short8*)(agl + off); pal1 = *(const short8*)(agl + off + 8);
      pbh0 = *(const short8*)(bgh + off); pbh1 = *(const short8*)(bgh + off + 8);
      pbl0 = *(const short8*)(bgl + off); pbl1 = *(const short8*)(bgl + off + 8);
    }
    short8 fah[4], fal[4], fbh[4], fbl[4];
#pragma unroll
    for (int i = 0; i < 4; ++i) {
      fah[i] = *(const short8*)&Ahs[wm + i * 16 + fr][fg * 8];
      fal[i] = *(const short8*)&Als[wm + i * 16 + fr][fg * 8];
    }
#pragma unroll
    for (int j = 0; j < 4; ++j) {
      fbh[j] = *(const short8*)&Bhs[wn + j * 16 + fr][fg * 8];
      fbl[j] = *(const short8*)&Bls[wn + j * 16 + fr][fg * 8];
    }
#pragma unroll
    for (int i = 0; i < 4; ++i)
#pragma unroll
      for (int j = 0; j < 4; ++j) {
        f32x4 t = MFMA(fah[i], fbh[j], acc[i][j]);
        t = MFMA(fal[i], fbh[j], t);
        t = MFMA(fah[i], fbl[j], t);
        acc[i][j] = t;
      }
  }

  const int rb = fg * 4;
#pragma unroll
  for (int i = 0; i < 4; ++i)
#pragma unroll
    for (int j = 0; j < 4; ++j) {
      const int n = n0 + wn + j * 16 + fr;
#pragma unroll
      for (int r = 0; r < 4; ++r) {
        const int m = m0 + wm + i * 16 + rb + r;
        Y[(size_t)m * N + n] = acc[i][j][r];
      }
    }
}

// ---------------------------------------------------------------- k_fin
__global__ __launch_bounds__(256) void k_fin(
    const ushort* __restrict__ A, const ushort* __restrict__ Bt,
    const float* __restrict__ b_vo, const float* __restrict__ b_ao,
    float* __restrict__ out)
{
  __shared__ __align__(16) ushort As[128][40];
  __shared__ __align__(16) ushort Bs[128][40];
  const int tid = threadIdx.x;
  const int m0 = blockIdx.x * 128, n0 = blockIdx.y * 128;
  const int w = tid >> 6, lane = tid & 63;
  const int wm = (w & 1) * 64, wn = (w >> 1) * 64;
  const int fr = lane & 15, fg = lane >> 4;
  const int K = KF;

  f32x4 acc[4][4];
#pragma unroll
  for (int i = 0; i < 4; ++i)
#pragma unroll
    for (int j = 0; j < 4; ++j) acc[i][j] = (f32x4){0.f, 0.f, 0.f, 0.f};

  const int sr = tid >> 1, sk = (tid & 1) * 16;
  const ushort* ag = A + (size_t)(m0 + sr) * K + sk;
  const ushort* bg = Bt + (size_t)(n0 + sr) * K + sk;
  short8 a0 = *(const short8*)ag;
  short8 a1 = *(const short8*)(ag + 8);
  short8 b0 = *(const short8*)bg;
  short8 b1 = *(const short8*)(bg + 8);

  const int NT = K >> 5;
  for (int kt = 0; kt < NT; ++kt) {
    __syncthreads();
    *(short8*)&As[sr][sk] = a0; *(short8*)&As[sr][sk + 8] = a1;
    *(short8*)&Bs[sr][sk] = b0; *(short8*)&Bs[sr][sk + 8] = b1;
    __syncthreads();
    if (kt + 1 < NT) {
      const ushort* agn = ag + (size_t)(kt + 1) * 32;
      const ushort* bgn = bg + (size_t)(kt + 1) * 32;
      a0 = *(const short8*)agn; a1 = *(const short8*)(agn + 8);
      b0 = *(const short8*)bgn; b1 = *(const short8*)(bgn + 8);
    }
    short8 aF[4], bF[4];
#pragma unroll
    for (int i = 0; i < 4; ++i) aF[i] = *(const short8*)&As[wm + i * 16 + fr][fg * 8];
#pragma unroll
    for (int j = 0; j < 4; ++j) bF[j] = *(const short8*)&Bs[wn + j * 16 + fr][fg * 8];
#pragma unroll
    for (int i = 0; i < 4; ++i)
#pragma unroll
      for (int j = 0; j < 4; ++j)
        acc[i][j] = MFMA(aF[i], bF[j], acc[i][j]);
  }

  const int rb = fg * 4;
#pragma unroll
  for (int j = 0; j < 4; ++j) {
    const int n = n0 + wn + j * 16 + fr;
    const float bias = b_vo[n] + b_ao[n];
#pragma unroll
    for (int i = 0; i < 4; ++i)
#pragma unroll
      for (int r = 0; r < 4; ++r) {
        const int m = m0 + wm + i * 16 + rb + r;
        out[(size_t)m * ND + n] = acc[i][j][r] + bias;
      }
  }
}

// ---------------------------------------------------------------- k_rope
__global__ __launch_bounds__(256) void k_rope(
    const float* __restrict__ Y,
    ushort* __restrict__ qAh, ushort* __restrict__ kBh,
    ushort* __restrict__ Vt)
{
  __shared__ float t0[64][65];
  __shared__ float t1[64][72];
  const int tid = threadIdx.x;
  const int l0 = blockIdx.x * 64, h = blockIdx.y;
  const int b = l0 >> 10, ll0 = l0 & 1023;
  const int bh = b * NH + h;
  const int rr = tid >> 6, cc = tid & 63;
  const float inv = powf(10000.f, -(float)(cc & ~1) / 64.f);
  const bool odd = (cc & 1) != 0;

  // ---- q (hi plane only, pre-scaled) ----
  for (int p = 0; p < 16; ++p) {
    const int r = p * 4 + rr;
    t0[r][cc] = Y[(size_t)(l0 + r) * NCAT + h * 64 + cc];
  }
  __syncthreads();
  for (int p = 0; p < 16; ++p) {
    const int r = p * 4 + rr;
    float sv, cv;
    __sincosf((float)(ll0 + r) * inv, &sv, &cv);
    const float e = t0[r][cc & ~1], o = t0[r][(cc & ~1) + 1];
    const float val = (odd ? fmaf(e, sv, o * cv) : fmaf(e, cv, -o * sv)) * SCL_S;
    qAh[((size_t)bh * NL + ll0 + r) * 128 + cc] = f2bf(val);
  }
  __syncthreads();
  // ---- k (hi plane only) ----
  for (int p = 0; p < 16; ++p) {
    const int r = p * 4 + rr;
    t0[r][cc] = Y[(size_t)(l0 + r) * NCAT + 512 + h * 64 + cc];
  }
  __syncthreads();
  for (int p = 0; p < 16; ++p) {
    const int r = p * 4 + rr;
    float sv, cv;
    __sincosf((float)(ll0 + r) * inv, &sv, &cv);
    const float e = t0[r][cc & ~1], o = t0[r][(cc & ~1) + 1];
    const float val = odd ? fmaf(e, sv, o * cv) : fmaf(e, cv, -o * sv);
    kBh[((size_t)bh * NL + ll0 + r) * 128 + cc] = f2bf(val);
  }
  // ---- v (transpose to Vt[dim][token]) ----
  for (int p = 0; p < 16; ++p) {
    const int r = p * 4 + rr;
    t1[cc][r] = Y[(size_t)(l0 + r) * NCAT + 1024 + h * 64 + cc];
  }
  __syncthreads();
  for (int p = 0; p < 16; ++p) {
    const int hd = p * 4 + rr;
    Vt[((size_t)bh * 112 + hd) * NL + ll0 + cc] = f2bf(t1[hd][cc]);
  }
  // zero Vt pad rows 103..111
  for (int u = tid; u < 9 * 64; u += 256)
    Vt[((size_t)bh * 112 + 103 + (u >> 6)) * NL + ll0 + (u & 63)] = 0;
}

// ---------------------------------------------------------------- k_rot
__global__ __launch_bounds__(256) void k_rot(
    const float* __restrict__ Y,
    const float* __restrict__ rots, const float* __restrict__ trans,
    const float* __restrict__ mask,
    const float* __restrict__ bvq, const float* __restrict__ bvk,
    const float* __restrict__ bvv, const float* __restrict__ baq,
    const float* __restrict__ bav,
    ushort* __restrict__ qAh, ushort* __restrict__ kBh,
    ushort* __restrict__ Vt,
    float* __restrict__ aq_t, float* __restrict__ penc)
{
  __shared__ float ys[8][912];
  const int tb = blockIdx.x * 8;
  const int b = tb >> 10;
  const int tid = threadIdx.x;

  for (int t = 0; t < 8; ++t)
    for (int n = tid; n < 912; n += 256)
      ys[t][n] = Y[(size_t)(tb + t) * NCAT + 1536 + n];
  __syncthreads();

  for (int u = tid; u < 8 * 288; u += 256) {
    const int t = u / 288, n = u % 288;
    const int l = tb + t, ll = l & (NL - 1);
    const int c = n % 3, base = n - c;
    const int h = n / NV3, m = n % NV3;
    const float r0 = rots[(size_t)l * 9 + c * 3 + 0];
    const float r1 = rots[(size_t)l * 9 + c * 3 + 1];
    const float r2 = rots[(size_t)l * 9 + c * 3 + 2];
    const float vqv = (r0 * (ys[t][base] + bvq[base])
                     + r1 * (ys[t][base + 1] + bvq[base + 1])
                     + r2 * (ys[t][base + 2] + bvq[base + 2])) * SCL_V;
    const float vkv = r0 * (ys[t][288 + base] + bvk[base])
                    + r1 * (ys[t][289 + base] + bvk[base + 1])
                    + r2 * (ys[t][290 + base] + bvk[base + 2]);
    const float vvv = r0 * (ys[t][576 + base] + bvv[base])
                    + r1 * (ys[t][577 + base] + bvv[base + 1])
                    + r2 * (ys[t][578 + base] + bvv[base + 2]);
    const size_t row = ((size_t)(b * NH + h) * NL + ll) * 128 + 64 + m;
    qAh[row] = f2bf(vqv);
    kBh[row] = f2bf(vkv);
    Vt[((size_t)(b * NH + h) * 112 + 64 + m) * NL + ll] = f2bf(vvv);
  }
  for (int u = tid; u < 8 * 8 * 14; u += 256) {
    const int t = u / 112, rem = u % 112, h = rem / 14, k = rem % 14;
    const int ll = (tb + t) & (NL - 1);
    const size_t row = ((size_t)(b * NH + h) * NL + ll) * 128 + 100 + 2 * k;
    *(uint*)&qAh[row] = 0;
  }
  for (int u = tid; u < 64; u += 256) {
    const int t = u >> 3, h = u & 7;
    const int l = tb + t, ll = l & (NL - 1);
    const int base = h * 3;
    const size_t tok = (size_t)(b * NH + h) * NL + ll;
#pragma unroll
    for (int c = 0; c < 3; ++c) {
      const float aqv =
          rots[(size_t)l * 9 + c * 3 + 0] * (ys[t][864 + base] + baq[base])
        + rots[(size_t)l * 9 + c * 3 + 1] * (ys[t][865 + base] + baq[base + 1])
        + rots[(size_t)l * 9 + c * 3 + 2] * (ys[t][866 + base] + baq[base + 2])
        + trans[(size_t)l * 3 + c];
      aq_t[((size_t)(b * NH + h) * 3 + c) * NL + ll] = aqv;
    }
#pragma unroll
    for (int k = 0; k < 14; ++k)
      *(uint*)&kBh[tok * 128 + 100 + 2 * k] = 0;
  }
  for (int u = tid; u < 8 * 24; u += 256) {
    const int t = u / 24, n = u % 24;
    const int l = tb + t, ll = l & (NL - 1);
    const int c = n % 3, h = n / 3, base = h * 3;
    const float val = rots[(size_t)l * 9 + c * 3 + 0] * (ys[t][888 + base] + bav[base])
                    + rots[(size_t)l * 9 + c * 3 + 1] * (ys[t][889 + base] + bav[base + 1])
                    + rots[(size_t)l * 9 + c * 3 + 2] * (ys[t][890 + base] + bav[base + 2])
                    + trans[(size_t)l * 3 + c];
    Vt[((size_t)(b * NH + h) * 112 + 100 + c) * NL + ll] = f2bf(val);
  }
  for (int u = tid; u < 8; u += 256) {
    const int ll = (tb + u) & (NL - 1);
    penc[(size_t)b * NL + ll] = 1e6f * (1.0f - mask[(size_t)b * NL + ll]);
  }
}

// ---------------------------------------------------------------- k_attn
// Flash MFMA attention, 16 q-rows/block, 4 independent j-quarter waves.
// XCD-swizzled (each XCD owns 2 bh slices -> K/V ~1.0 MB L2-resident).
// Single-bf16 q x k (distance path exact fp32); regs < 128 bucket.
__global__ __launch_bounds__(256) void k_attn(
    const ushort* __restrict__ qAh,
    const ushort* __restrict__ kBh, const ushort* __restrict__ Vt,
    const float* __restrict__ aq_t, const float* __restrict__ penc,
    const float* __restrict__ rots, const float* __restrict__ trans,
    const float* __restrict__ affw,
    ushort* __restrict__ catb)
{
  __shared__ __align__(16) ushort P_s[4][16][72];
  __shared__ float Ocmb[4][16][112];
  __shared__ float mst[4][16], lst[4][16];
  __shared__ float fac[4][16];
  __shared__ float linv[16];

  const int blk = blockIdx.x;
  const int bh  = (blk & 7) * 2 + (blk >> 9);
  const int i0  = ((blk >> 3) & 63) * 16;
  const int b = bh >> 3, h = bh & 7;
  const int tid = threadIdx.x;
  const int w = tid >> 6, lane = tid & 63;
  const int fr = lane & 15, fg = lane >> 4;

  const float spw = logf(1.0f + expf(affw[h]));

  short8 aQh[4];
  const size_t qrow = ((size_t)bh * NL + i0 + fr) * 128;
#pragma unroll
  for (int ks = 0; ks < 4; ++ks)
    aQh[ks] = *(const short8*)&qAh[qrow + ks * 32 + fg * 8];

  const float* aqx = aq_t + (size_t)bh * 3 * NL;
  float ai0[4], ai1[4], ai2[4];
#pragma unroll
  for (int r_ = 0; r_ < 4; ++r_) {
    const int row = i0 + fg * 4 + r_;
    ai0[r_] = aqx[row];
    ai1[r_] = aqx[NL + row];
    ai2[r_] = aqx[2 * NL + row];
  }

  float mrun[4], lrun[4];
#pragma unroll
  for (int r_ = 0; r_ < 4; ++r_) { mrun[r_] = -3.0e38f; lrun[r_] = 0.f; }

  f32x4 accO[7];
#pragma unroll
  for (int ct = 0; ct < 7; ++ct) accO[ct] = (f32x4){0.f, 0.f, 0.f, 0.f};

  const size_t kbase = (size_t)bh * NL * 128;
  const size_t vbase = (size_t)bh * 112 * NL;

  for (int jt = 0; jt < 4; ++jt) {
    const int j0 = w * 256 + jt * 64;

    f32x4 accS[4];
#pragma unroll
    for (int ct = 0; ct < 4; ++ct) accS[ct] = (f32x4){0.f, 0.f, 0.f, 0.f};
#pragma unroll
    for (int ct = 0; ct < 4; ++ct) {
      const size_t rowb = kbase + (size_t)(j0 + ct * 16 + fr) * 128;
#pragma unroll
      for (int ks = 0; ks < 4; ++ks) {
        const short8 bh8 = *(const short8*)&kBh[rowb + ks * 32 + fg * 8];
        accS[ct] = MFMA(aQh[ks], bh8, accS[ct]);
      }
    }

    // exact fp32 distances + penalty, online softmax (accS reused in place)
    float smax[4] = {-3.0e38f, -3.0e38f, -3.0e38f, -3.0e38f};
#pragma unroll
    for (int ct = 0; ct < 4; ++ct) {
      const int j = j0 + ct * 16 + fr;
      const float aj0 = aqx[j];
      const float aj1 = aqx[NL + j];
      const float aj2v = aqx[2 * NL + j];
      const float pen = penc[(size_t)b * NL + j];
#pragma unroll
      for (int r_ = 0; r_ < 4; ++r_) {
        const float dx = ai0[r_] - aj0;
        const float dy = ai1[r_] - aj1;
        const float dz = ai2[r_] - aj2v;
        const float s = accS[ct][r_]
                      - spw * sqrtf(dx * dx + dy * dy + dz * dz) - pen;
        accS[ct][r_] = s;
        smax[r_] = fmaxf(smax[r_], s);
      }
    }
#pragma unroll
    for (int off = 1; off < 16; off <<= 1) {
#pragma unroll
      for (int r_ = 0; r_ < 4; ++r_)
        smax[r_] = fmaxf(smax[r_], __shfl_xor(smax[r_], off));
    }
    float scale[4], lsum[4];
#pragma unroll
    for (int r_ = 0; r_ < 4; ++r_) {
      const float mnew = fmaxf(mrun[r_], smax[r_]);
      scale[r_] = __expf(mrun[r_] - mnew);
      mrun[r_] = mnew;
      lsum[r_] = 0.f;
    }
#pragma unroll
    for (int ct = 0; ct < 4; ++ct)
#pragma unroll
      for (int r_ = 0; r_ < 4; ++r_) {
        const float p = __expf(accS[ct][r_] - mrun[r_]);
        accS[ct][r_] = p;
        lsum[r_] += p;
      }
#pragma unroll
    for (int off = 1; off < 16; off <<= 1) {
#pragma unroll
      for (int r_ = 0; r_ < 4; ++r_) lsum[r_] += __shfl_xor(lsum[r_], off);
    }
#pragma unroll
    for (int r_ = 0; r_ < 4; ++r_) lrun[r_] = lrun[r_] * scale[r_] + lsum[r_];
#pragma unroll
    for (int ct = 0; ct < 7; ++ct)
#pragma unroll
      for (int r_ = 0; r_ < 4; ++r_) accO[ct][r_] *= scale[r_];

    // P tile to this wave's private LDS region (same-wave ordering via lgkmcnt)
#pragma unroll
    for (int ct = 0; ct < 4; ++ct)
#pragma unroll
      for (int r_ = 0; r_ < 4; ++r_)
        P_s[w][fg * 4 + r_][ct * 16 + fr] = f2bf(accS[ct][r_]);

    const short8 aP0 = *(const short8*)&P_s[w][fr][fg * 8];
    const short8 aP1 = *(const short8*)&P_s[w][fr][32 + fg * 8];
#pragma unroll
    for (int ct = 0; ct < 7; ++ct) {
      const size_t vrow = vbase + (size_t)(ct * 16 + fr) * NL + j0;
      const short8 b0 = *(const short8*)&Vt[vrow + fg * 8];
      const short8 b1 = *(const short8*)&Vt[vrow + 32 + fg * 8];
      f32x4 t = MFMA(aP0, b0, accO[ct]);
      accO[ct] = MFMA(aP1, b1, t);
    }
  }

  // publish partials
#pragma unroll
  for (int ct = 0; ct < 7; ++ct)
#pragma unroll
    for (int r_ = 0; r_ < 4; ++r_)
      Ocmb[w][fg * 4 + r_][ct * 16 + fr] = accO[ct][r_];
  if (fr == 0) {
#pragma unroll
    for (int r_ = 0; r_ < 4; ++r_) {
      mst[w][fg * 4 + r_] = mrun[r_];
      lst[w][fg * 4 + r_] = lrun[r_];
    }
  }
  __syncthreads();

  if (tid < 16) {
    const float m0 = mst[0][tid], m1 = mst[1][tid];
    const float m2 = mst[2][tid], m3 = mst[3][tid];
    const float M = fmaxf(fmaxf(m0, m1), fmaxf(m2, m3));
    const float e0 = __expf(m0 - M), e1 = __expf(m1 - M);
    const float e2 = __expf(m2 - M), e3 = __expf(m3 - M);
    const float L = lst[0][tid] * e0 + lst[1][tid] * e1
                  + lst[2][tid] * e2 + lst[3][tid] * e3;
    fac[0][tid] = e0; fac[1][tid] = e1; fac[2][tid] = e2; fac[3][tid] = e3;
    linv[tid] = 1.0f / L;
  }
  __syncthreads();

  for (int u = tid; u < 16 * 112; u += 256) {
    const int row = u / 112, d = u % 112;
    const float val = (Ocmb[0][row][d] * fac[0][row]
                     + Ocmb[1][row][d] * fac[1][row]
                     + Ocmb[2][row][d] * fac[2][row]
                     + Ocmb[3][row][d] * fac[3][row]) * linv[row];
    Ocmb[0][row][d] = val;
  }
  __syncthreads();

  // epilogue: rotations + catb writes
  for (int u = tid; u < 16 * 103; u += 256) {
    const int lr = u / 103, d = u % 103;
    const int gi = i0 + lr;
    const size_t gl = (size_t)b * NL + gi;
    const float* O = Ocmb[0][lr];
    float val;
    int col;
    if (d < 64) {
      val = O[d];
      col = h * 64 + d;
    } else if (d < 100) {
      const int v3 = d - 64;
      const int n = v3 % 3;
      const int base = 64 + v3 - n;
      val = O[base] * rots[gl * 9 + n] + O[base + 1] * rots[gl * 9 + 3 + n]
          + O[base + 2] * rots[gl * 9 + 6 + n];
      col = 512 + h * NV3 + v3;
    } else {
      const int n = d - 100;
      const float c0 = O[100] - trans[gl * 3 + 0];
      const float c1 = O[101] - trans[gl * 3 + 1];
      const float c2 = O[102] - trans[gl * 3 + 2];
      val = c0 * rots[gl * 9 + n] + c1 * rots[gl * 9 + 3 + n] + c2 * rots[gl * 9 + 6 + n];
      col = 800 + h * 3 + n;
    }
    catb[gl * KF + col] = f2bf(val);
  }
  if (h == 0) {
    for (int u = tid; u < 16 * 8; u += 256)
      catb[((size_t)b * NL + i0 + (u >> 3)) * KF + 824 + (u & 7)] = 0;
  }
}

} // namespace

extern "C" void kernel_launch(void* const* d_in, const int* in_sizes, int n_in,
                              void* d_out, int out_size, void* d_ws, size_t ws_size,
                              hipStream_t stream)
{
  const float* x       = (const float*)d_in[0];
  const float* mask    = (const float*)d_in[1];
  const float* rots    = (const float*)d_in[2];
  const float* trans   = (const float*)d_in[3];
  const float* w_q     = (const float*)d_in[4];
  const float* w_k     = (const float*)d_in[5];
  const float* w_v     = (const float*)d_in[6];
  const float* w_o     = (const float*)d_in[7];
  const float* w_vq_w  = (const float*)d_in[8];
  const float* w_vq_b  = (const float*)d_in[9];
  const float* w_vk_w  = (const float*)d_in[10];
  const float* w_vk_b  = (const float*)d_in[11];
  const float* w_vv_w  = (const float*)d_in[12];
  const float* w_vv_b  = (const float*)d_in[13];
  const float* w_vo_w  = (const float*)d_in[14];
  const float* w_vo_b  = (const float*)d_in[15];
  const float* w_aq_w  = (const float*)d_in[16];
  const float* w_aq_b  = (const float*)d_in[17];
  const float* w_av_w  = (const float*)d_in[18];
  const float* w_av_b  = (const float*)d_in[19];
  const float* w_ao_w  = (const float*)d_in[20];
  const float* w_ao_b  = (const float*)d_in[21];
  const float* aff_w   = (const float*)d_in[22];
  float* out = (float*)d_out;

  char* base = (char*)d_ws;
  ushort* xh  = (ushort*)base;
  ushort* xl  = xh + (size_t)2048 * 512;
  ushort* wch = xl + (size_t)2048 * 512;
  ushort* wcl = wch + (size_t)2560 * 512;
  ushort* qAh = (ushort*)base;                       // 4 MB (over xh+xl)
  float*  aq_t = (float*)(qAh + (size_t)16 * 1024 * 128);  // 196 KB (over wch)
  char* p = base + 9437184;
  ushort* wcat2 = (ushort*)p; p += (size_t)512 * 832 * 2;
  float*  Y     = (float*)p;
  ushort* catb  = (ushort*)Y;
  p += (size_t)2048 * 2560 * 4;
  ushort* kBh = (ushort*)p; p += (size_t)16 * 1024 * 128 * 2;
  ushort* Vt  = (ushort*)p; p += (size_t)16 * 112 * 1024 * 2;
  float* penc = (float*)p;  p += (size_t)2048 * 4;

  k_pack<<<dim3(40, 13, 2), 256, 0, stream>>>(w_q, w_k, w_v, w_vq_w, w_vk_w,
                                              w_vv_w, w_aq_w, w_av_w,
                                              w_o, w_vo_w, w_ao_w,
                                              wch, wcl, wcat2);
  k_cvtx<<<1024, 256, 0, stream>>>(x, xh, xl);
  k_mm<<<dim3(16, 20), 256, 0, stream>>>(xh, xl, wch, wcl, Y, NCAT, 512);
  k_rope<<<dim3(32, 8), 256, 0, stream>>>(Y, qAh, kBh, Vt);
  k_rot<<<256, 256, 0, stream>>>(Y, rots, trans, mask,
                                 w_vq_b, w_vk_b, w_vv_b, w_aq_b, w_av_b,
                                 qAh, kBh, Vt, aq_t, penc);
  k_attn<<<1024, 256, 0, stream>>>(qAh, kBh, Vt,
                                   aq_t, penc, rots, trans, aff_w, catb);
  k_fin<<<dim3(16, 4), 256, 0, stream>>>(catb, wcat2, w_vo_b, w_ao_b, out);
}